// Round 6
// baseline (246.953 us; speedup 1.0000x reference)
//
#include <hip/hip_runtime.h>
#include <hip/hip_bf16.h>
#include <stdint.h>

#define NROWS 8192
#define DIMQ 1024
#define DIMU 1024
#define NCH 16

#define BM 128
#define BN 128
#define BK 64
#define LDSTR 72   // bf16 elems per LDS row: 144B stride spreads b128/b64 ops across bank groups

typedef __attribute__((ext_vector_type(4))) float f32x4;
typedef __attribute__((ext_vector_type(4))) short s16x4;
typedef __attribute__((ext_vector_type(8))) short bf16x8;

__device__ __forceinline__ short f2bf(float f) {
    union { __hip_bfloat16 h; short s; } u;
    u.h = __float2bfloat16(f);
    return u.s;
}

// ---------------- f32 -> bf16 convert for W_stack only (q converted in-GEMM) ----------------
__global__ void cvtW_kernel(const float* __restrict__ Ws, short* __restrict__ Wb) {
    const int nw = NCH * DIMU * DIMQ / 8;
    int i = blockIdx.x * blockDim.x + threadIdx.x;
    int stride = gridDim.x * blockDim.x;
    for (; i < nw; i += stride) {
        const f32x4* p = reinterpret_cast<const f32x4*>(Ws + (size_t)i * 8);
        f32x4 a = p[0], b = p[1];
        bf16x8 o;
        o[0] = f2bf(a[0]); o[1] = f2bf(a[1]); o[2] = f2bf(a[2]); o[3] = f2bf(a[3]);
        o[4] = f2bf(b[0]); o[5] = f2bf(b[1]); o[6] = f2bf(b[2]); o[7] = f2bf(b[3]);
        *reinterpret_cast<bf16x8*>(Wb + (size_t)i * 8) = o;
    }
}

// ---------------- gate: top-2 + normalize, LDS histogram ----------------
__global__ void gate_kernel(const float* __restrict__ weights,
                            int* __restrict__ cnt,
                            int* __restrict__ rowlist,
                            float* __restrict__ wgt) {
    __shared__ int lcnt[NCH];
    __shared__ int lbase[NCH];
    const int t = threadIdx.x;
    const int b = blockIdx.x * blockDim.x + t;
    if (t < NCH) lcnt[t] = 0;
    __syncthreads();

    float w[NCH];
    const f32x4* wp = reinterpret_cast<const f32x4*>(weights + (size_t)b * NCH);
#pragma unroll
    for (int i = 0; i < 4; ++i) {
        f32x4 v = wp[i];
        w[i * 4 + 0] = v[0]; w[i * 4 + 1] = v[1];
        w[i * 4 + 2] = v[2]; w[i * 4 + 3] = v[3];
    }
    int i0 = 0; float v0 = w[0];
#pragma unroll
    for (int i = 1; i < NCH; ++i) if (w[i] > v0) { v0 = w[i]; i0 = i; }
    int i1 = (i0 == 0) ? 1 : 0; float v1 = w[i1];
#pragma unroll
    for (int i = 0; i < NCH; ++i) if (i != i0 && w[i] > v1) { v1 = w[i]; i1 = i; }
    float s = v0 + v1;
    s = (s < 1e-8f) ? 1e-8f : s;
    float n0 = v0 / s, n1 = v1 / s;

    int p0 = atomicAdd(&lcnt[i0], 1);
    int p1 = atomicAdd(&lcnt[i1], 1);
    __syncthreads();
    if (t < NCH) lbase[t] = atomicAdd(&cnt[t], lcnt[t]);
    __syncthreads();

    int o0 = lbase[i0] + p0;
    int o1 = lbase[i1] + p1;
    rowlist[(size_t)i0 * NROWS + o0] = b;  wgt[(size_t)i0 * NROWS + o0] = n0;
    rowlist[(size_t)i1 * NROWS + o1] = b;  wgt[(size_t)i1 * NROWS + o1] = n1;
}

// ================= grouped gather-GEMM (round-3 proven structure) =================
// A read directly from f32 q (converted during LDS staging); B from pre-converted bf16 W.
// Reg-staged loads issued before the MFMA phase (latency hidden), padded LDS, flat 3D
// grid with early-exit (round-3's measured-best shape; no XCD pinning — it regressed).
__global__ __launch_bounds__(256, 3) void moe_gemm_bf(
    const float* __restrict__ q, const short* __restrict__ Wb,
    const int* __restrict__ cnt, const int* __restrict__ rowlist,
    const float* __restrict__ wgt, float* __restrict__ out)
{
    const int c  = blockIdx.z;
    const int n0 = blockIdx.x * BN;
    const int m0 = blockIdx.y * BM;
    const int count = cnt[c];
    if (m0 >= count) return;

    __shared__ short sA[BM * LDSTR];
    __shared__ short sB[BN * LDSTR];
    __shared__ int   sRow[BM];
    __shared__ float sW[BM];

    const int t = threadIdx.x;
    if (t < BM) {
        int gi = m0 + t;
        int r = 0; float wv_ = 0.f;
        if (gi < count) {
            r   = rowlist[(size_t)c * NROWS + gi];
            wv_ = wgt[(size_t)c * NROWS + gi];
        }
        sRow[t] = r; sW[t] = wv_;
    }
    __syncthreads();

    // A staging (f32): tile = 128 rows x 64 f32 = 2048 chunks of 4 f32 (16B); 8 chunks/thread
    const float* aSrc[8];
    int aO[8];
#pragma unroll
    for (int i = 0; i < 8; ++i) {
        int ch = i * 256 + t;
        int r  = ch >> 4;
        int q4 = ch & 15;
        aSrc[i] = q + (size_t)sRow[r] * DIMQ + q4 * 4;
        aO[i]   = r * LDSTR + q4 * 4;
    }
    // B staging (bf16): 128 rows x 64 bf16 = 1024 chunks of 8 bf16 (16B); 4 chunks/thread
    const short* bSrc[4];
    int bO[4];
#pragma unroll
    for (int i = 0; i < 4; ++i) {
        int ch = i * 256 + t;
        int r  = ch >> 3;
        int c8 = ch & 7;
        bSrc[i] = Wb + (size_t)c * ((size_t)DIMU * DIMQ) + (size_t)(n0 + r) * DIMQ + c8 * 8;
        bO[i]   = r * LDSTR + c8 * 8;
    }

    const int lane = t & 63;
    const int wv   = t >> 6;
    const int wm   = (wv >> 1) * 64;
    const int wn   = (wv & 1) * 64;
    const int rr   = lane & 15;
    const int g    = lane >> 4;

    f32x4 acc[4][4];
#pragma unroll
    for (int r = 0; r < 4; ++r)
#pragma unroll
        for (int cc = 0; cc < 4; ++cc)
            acc[r][cc] = (f32x4){0.f, 0.f, 0.f, 0.f};

    f32x4  pa[8];
    bf16x8 pb[4];
#pragma unroll
    for (int i = 0; i < 8; ++i) pa[i] = *reinterpret_cast<const f32x4*>(aSrc[i]);
#pragma unroll
    for (int i = 0; i < 4; ++i) pb[i] = *reinterpret_cast<const bf16x8*>(bSrc[i]);

    const int NKT = DIMQ / BK;  // 16
    for (int kt = 0; kt < NKT; ++kt) {
        __syncthreads();   // previous iter's ds_reads done before LDS overwrite
#pragma unroll
        for (int i = 0; i < 8; ++i) {
            s16x4 va;
#pragma unroll
            for (int j = 0; j < 4; ++j) va[j] = f2bf(pa[i][j]);
            *reinterpret_cast<s16x4*>(&sA[aO[i]]) = va;
        }
#pragma unroll
        for (int i = 0; i < 4; ++i)
            *reinterpret_cast<bf16x8*>(&sB[bO[i]]) = pb[i];
        __syncthreads();

        if (kt + 1 < NKT) {   // issue next tile's loads; latency hides under the MFMA phase
            int k = (kt + 1) * BK;
#pragma unroll
            for (int i = 0; i < 8; ++i) pa[i] = *reinterpret_cast<const f32x4*>(aSrc[i] + k);
#pragma unroll
            for (int i = 0; i < 4; ++i) pb[i] = *reinterpret_cast<const bf16x8*>(bSrc[i] + k);
        }

#pragma unroll
        for (int ks = 0; ks < 2; ++ks) {
            bf16x8 af[4], bfr[4];
#pragma unroll
            for (int r = 0; r < 4; ++r) {
                af[r]  = *reinterpret_cast<const bf16x8*>(&sA[(wm + r * 16 + rr) * LDSTR + ks * 32 + g * 8]);
                bfr[r] = *reinterpret_cast<const bf16x8*>(&sB[(wn + r * 16 + rr) * LDSTR + ks * 32 + g * 8]);
            }
#pragma unroll
            for (int r = 0; r < 4; ++r)
#pragma unroll
                for (int cc = 0; cc < 4; ++cc)
                    acc[r][cc] = __builtin_amdgcn_mfma_f32_16x16x32_bf16(af[r], bfr[cc], acc[r][cc], 0, 0, 0);
        }
    }

    // epilogue: gate-scale + scatter-add (each out element hit by exactly 2 charts)
#pragma unroll
    for (int r = 0; r < 4; ++r) {
#pragma unroll
        for (int cc = 0; cc < 4; ++cc) {
#pragma unroll
            for (int j = 0; j < 4; ++j) {
                int rowInTile = wm + r * 16 + g * 4 + j;   // C/D: row=(lane>>4)*4+reg, col=lane&15 (m89)
                int gi = m0 + rowInTile;
                if (gi < count) {
                    int   orow = sRow[rowInTile];
                    float wgx  = sW[rowInTile];
                    int   col  = n0 + wn + cc * 16 + rr;
                    atomicAdd(&out[(size_t)orow * DIMU + col], acc[r][cc][j] * wgx);
                }
            }
        }
    }
}

// ================= fallback f32-staging GEMM (proven round-2 path) =================
#define BKF 32
#define LDSTRF 40

__global__ __launch_bounds__(256, 2) void moe_gemm_f32(
    const float* __restrict__ q, const float* __restrict__ Wst,
    const int* __restrict__ cnt, const int* __restrict__ rowlist,
    const float* __restrict__ wgt, float* __restrict__ out)
{
    const int c  = blockIdx.z;
    const int n0 = blockIdx.x * BN;
    const int m0 = blockIdx.y * BM;
    const int count = cnt[c];
    if (m0 >= count) return;

    __shared__ short sA[BM * LDSTRF];
    __shared__ short sB[BN * LDSTRF];
    __shared__ int   sRow[BM];
    __shared__ float sW[BM];

    const int t = threadIdx.x;
    if (t < BM) {
        int gi = m0 + t;
        int r = 0; float w = 0.f;
        if (gi < count) {
            r = rowlist[(size_t)c * NROWS + gi];
            w = wgt[(size_t)c * NROWS + gi];
        }
        sRow[t] = r; sW[t] = w;
    }
    __syncthreads();

    const float* aBase[4];
    const float* bBase[4];
    int ldsOff[4];
#pragma unroll
    for (int i = 0; i < 4; ++i) {
        int f  = t + i * 256;
        int r  = f >> 3;
        int c4 = f & 7;
        aBase[i]  = q   + (size_t)sRow[r] * DIMQ + c4 * 4;
        bBase[i]  = Wst + (size_t)c * ((size_t)DIMU * DIMQ) + (size_t)(n0 + r) * DIMQ + c4 * 4;
        ldsOff[i] = r * LDSTRF + c4 * 4;
    }

    const int lane = t & 63;
    const int wv   = t >> 6;
    const int wm   = (wv >> 1) * 64;
    const int wn   = (wv & 1) * 64;
    const int rr   = lane & 15;
    const int g    = lane >> 4;

    f32x4 acc[4][4];
#pragma unroll
    for (int r = 0; r < 4; ++r)
#pragma unroll
        for (int cc = 0; cc < 4; ++cc)
            acc[r][cc] = (f32x4){0.f, 0.f, 0.f, 0.f};

    f32x4 pa[4], pb[4];
#pragma unroll
    for (int i = 0; i < 4; ++i) {
        pa[i] = *reinterpret_cast<const f32x4*>(aBase[i]);
        pb[i] = *reinterpret_cast<const f32x4*>(bBase[i]);
    }

    const int NKT = DIMQ / BKF;
    for (int kt = 0; kt < NKT; ++kt) {
        __syncthreads();
#pragma unroll
        for (int i = 0; i < 4; ++i) {
            s16x4 va, vb;
#pragma unroll
            for (int j = 0; j < 4; ++j) { va[j] = f2bf(pa[i][j]); vb[j] = f2bf(pb[i][j]); }
            *reinterpret_cast<s16x4*>(&sA[ldsOff[i]]) = va;
            *reinterpret_cast<s16x4*>(&sB[ldsOff[i]]) = vb;
        }
        __syncthreads();

        if (kt + 1 < NKT) {
            int k = (kt + 1) * BKF;
#pragma unroll
            for (int i = 0; i < 4; ++i) {
                pa[i] = *reinterpret_cast<const f32x4*>(aBase[i] + k);
                pb[i] = *reinterpret_cast<const f32x4*>(bBase[i] + k);
            }
        }

        bf16x8 af[4], bfr[4];
#pragma unroll
        for (int r = 0; r < 4; ++r) {
            af[r]  = *reinterpret_cast<const bf16x8*>(&sA[(wm + r * 16 + rr) * LDSTRF + g * 8]);
            bfr[r] = *reinterpret_cast<const bf16x8*>(&sB[(wn + r * 16 + rr) * LDSTRF + g * 8]);
        }
#pragma unroll
        for (int r = 0; r < 4; ++r)
#pragma unroll
            for (int cc = 0; cc < 4; ++cc)
                acc[r][cc] = __builtin_amdgcn_mfma_f32_16x16x32_bf16(af[r], bfr[cc], acc[r][cc], 0, 0, 0);
    }

#pragma unroll
    for (int r = 0; r < 4; ++r) {
#pragma unroll
        for (int cc = 0; cc < 4; ++cc) {
#pragma unroll
            for (int j = 0; j < 4; ++j) {
                int rowInTile = wm + r * 16 + g * 4 + j;
                int gi = m0 + rowInTile;
                if (gi < count) {
                    int   orow = sRow[rowInTile];
                    float w    = sW[rowInTile];
                    int   col  = n0 + wn + cc * 16 + rr;
                    atomicAdd(&out[(size_t)orow * DIMU + col], acc[r][cc][j] * w);
                }
            }
        }
    }
}

extern "C" void kernel_launch(void* const* d_in, const int* in_sizes, int n_in,
                              void* d_out, int out_size, void* d_ws, size_t ws_size,
                              hipStream_t stream) {
    const float* q  = (const float*)d_in[0];
    const float* w  = (const float*)d_in[1];
    const float* Ws = (const float*)d_in[2];
    float* out = (float*)d_out;

    const size_t wbf_bytes  = (size_t)NCH * DIMU * (size_t)DIMQ * 2; // 33.55 MB
    const size_t meta_bytes = 256 + (size_t)NCH * NROWS * (sizeof(int) + sizeof(float));
    char* ws = (char*)d_ws;

    if (ws_size >= wbf_bytes + meta_bytes) {
        short* Wb      = (short*)ws;
        int*   cnt     = (int*)(ws + wbf_bytes);
        int*   rowlist = (int*)(ws + wbf_bytes + 256);
        float* wgt     = (float*)(ws + wbf_bytes + 256 + (size_t)NCH * NROWS * sizeof(int));

        hipMemsetAsync(cnt, 0, 256, stream);
        hipMemsetAsync(d_out, 0, (size_t)out_size * sizeof(float), stream);

        cvtW_kernel<<<2048, 256, 0, stream>>>(Ws, Wb);
        gate_kernel<<<NROWS / 256, 256, 0, stream>>>(w, cnt, rowlist, wgt);

        dim3 grid(DIMU / BN, NROWS / BM, NCH);   // round-3 measured-best grid shape
        moe_gemm_bf<<<grid, 256, 0, stream>>>(q, Wb, cnt, rowlist, wgt, out);
    } else {
        int*   cnt     = (int*)ws;
        int*   rowlist = (int*)(ws + 256);
        float* wgt     = (float*)(ws + 256 + (size_t)NCH * NROWS * sizeof(int));

        hipMemsetAsync(cnt, 0, 256, stream);
        hipMemsetAsync(d_out, 0, (size_t)out_size * sizeof(float), stream);

        gate_kernel<<<NROWS / 256, 256, 0, stream>>>(w, cnt, rowlist, wgt);

        dim3 grid(DIMU / BN, NROWS / BM, NCH);
        moe_gemm_f32<<<grid, 256, 0, stream>>>(q, Ws, cnt, rowlist, wgt, out);
    }
}

// Round 8
// 245.962 us; speedup vs baseline: 1.0040x; 1.0040x over previous
//
#include <hip/hip_runtime.h>
#include <hip/hip_bf16.h>
#include <stdint.h>

#define NROWS 8192
#define DIMQ 1024
#define DIMU 1024
#define NCH 16

#define BM 128
#define BN 128
#define BK 64

typedef __attribute__((ext_vector_type(4))) float f32x4;
typedef __attribute__((ext_vector_type(4))) short s16x4;
typedef __attribute__((ext_vector_type(8))) short bf16x8;

__device__ __forceinline__ short f2bf(float f) {
    union { __hip_bfloat16 h; short s; } u;
    u.h = __float2bfloat16(f);
    return u.s;
}

// ---------------- fused f32 -> bf16 convert for q and W_stack (R3 proven) ----------------
__global__ void cvt2_kernel(const float* __restrict__ q, const float* __restrict__ Ws,
                            short* __restrict__ qb, short* __restrict__ Wb) {
    const int nq = NROWS * DIMQ / 8;
    const int nw = NCH * DIMU * DIMQ / 8;
    int i0 = blockIdx.x * blockDim.x + threadIdx.x;
    int stride = gridDim.x * blockDim.x;
    for (int i = i0; i < nq; i += stride) {
        const f32x4* p = reinterpret_cast<const f32x4*>(q + (size_t)i * 8);
        f32x4 a = p[0], b = p[1];
        bf16x8 o;
        o[0] = f2bf(a[0]); o[1] = f2bf(a[1]); o[2] = f2bf(a[2]); o[3] = f2bf(a[3]);
        o[4] = f2bf(b[0]); o[5] = f2bf(b[1]); o[6] = f2bf(b[2]); o[7] = f2bf(b[3]);
        *reinterpret_cast<bf16x8*>(qb + (size_t)i * 8) = o;
    }
    for (int i = i0; i < nw; i += stride) {
        const f32x4* p = reinterpret_cast<const f32x4*>(Ws + (size_t)i * 8);
        f32x4 a = p[0], b = p[1];
        bf16x8 o;
        o[0] = f2bf(a[0]); o[1] = f2bf(a[1]); o[2] = f2bf(a[2]); o[3] = f2bf(a[3]);
        o[4] = f2bf(b[0]); o[5] = f2bf(b[1]); o[6] = f2bf(b[2]); o[7] = f2bf(b[3]);
        *reinterpret_cast<bf16x8*>(Wb + (size_t)i * 8) = o;
    }
}

// ---------------- gate: top-2 + normalize, LDS histogram ----------------
__global__ void gate_kernel(const float* __restrict__ weights,
                            int* __restrict__ cnt,
                            int* __restrict__ rowlist,
                            float* __restrict__ wgt) {
    __shared__ int lcnt[NCH];
    __shared__ int lbase[NCH];
    const int t = threadIdx.x;
    const int b = blockIdx.x * blockDim.x + t;
    if (t < NCH) lcnt[t] = 0;
    __syncthreads();

    float w[NCH];
    const f32x4* wp = reinterpret_cast<const f32x4*>(weights + (size_t)b * NCH);
#pragma unroll
    for (int i = 0; i < 4; ++i) {
        f32x4 v = wp[i];
        w[i * 4 + 0] = v[0]; w[i * 4 + 1] = v[1];
        w[i * 4 + 2] = v[2]; w[i * 4 + 3] = v[3];
    }
    int i0 = 0; float v0 = w[0];
#pragma unroll
    for (int i = 1; i < NCH; ++i) if (w[i] > v0) { v0 = w[i]; i0 = i; }
    int i1 = (i0 == 0) ? 1 : 0; float v1 = w[i1];
#pragma unroll
    for (int i = 0; i < NCH; ++i) if (i != i0 && w[i] > v1) { v1 = w[i]; i1 = i; }
    float s = v0 + v1;
    s = (s < 1e-8f) ? 1e-8f : s;
    float n0 = v0 / s, n1 = v1 / s;

    int p0 = atomicAdd(&lcnt[i0], 1);
    int p1 = atomicAdd(&lcnt[i1], 1);
    __syncthreads();
    if (t < NCH) lbase[t] = atomicAdd(&cnt[t], lcnt[t]);
    __syncthreads();

    int o0 = lbase[i0] + p0;
    int o1 = lbase[i1] + p1;
    rowlist[(size_t)i0 * NROWS + o0] = b;  wgt[(size_t)i0 * NROWS + o0] = n0;
    rowlist[(size_t)i1 * NROWS + o1] = b;  wgt[(size_t)i1 * NROWS + o1] = n1;
}

// ================= bf16 grouped gather-GEMM — pipelined dbuf gload_lds =================
// T3-minimum 2-phase pipeline (m230 recipe): STAGE(next tile -> other buffer) issued
// BEFORE computing current buffer; ONE __syncthreads per K-step (its vmcnt/lgkm drain
// lands after the MFMA phase covered the load latency). Both-sides XOR swizzle
// (rule #21): inverse-swizzled GLOBAL source col (c16^(r&7)), linear LDS dest
// (gload_lds requires it), XOR'd ds_read -> 2-way conflicts only.
__global__ __launch_bounds__(256, 2) void moe_gemm_bf(
    const short* __restrict__ qb, const short* __restrict__ Wb,
    const int* __restrict__ cnt, const int* __restrict__ rowlist,
    const float* __restrict__ wgt, float* __restrict__ out)
{
    const int c  = blockIdx.z;
    const int n0 = blockIdx.x * BN;
    const int m0 = blockIdx.y * BM;
    const int count = cnt[c];
    if (m0 >= count) return;

    __shared__ short sA[2][BM * BK];   // 2 x 16 KB, linear
    __shared__ short sB[2][BN * BK];   // 2 x 16 KB
    __shared__ int   sRow[BM];
    __shared__ float sW[BM];

    const int t = threadIdx.x;
    if (t < BM) {
        int gi = m0 + t;
        int r = 0; float wv_ = 0.f;
        if (gi < count) {
            r   = rowlist[(size_t)c * NROWS + gi];
            wv_ = wgt[(size_t)c * NROWS + gi];
        }
        sRow[t] = r; sW[t] = wv_;
    }
    __syncthreads();

    // staging map: tile = 128 rows x 64 bf16 = 1024 x 16B chunks; ch = i*256 + t
    // source col pre-XORed so linear LDS holds the swizzled layout (rule #21)
    const short* aS[4];
    const short* bS[4];
    int ldsO[4];
#pragma unroll
    for (int i = 0; i < 4; ++i) {
        int ch  = i * 256 + t;
        int r   = ch >> 3;
        int c16 = ch & 7;
        int cs  = (c16 ^ (r & 7)) * 8;   // inverse-swizzled source column (shorts)
        aS[i]   = qb + (size_t)sRow[r] * DIMQ + cs;
        bS[i]   = Wb + (size_t)c * ((size_t)DIMU * DIMQ) + (size_t)(n0 + r) * DIMQ + cs;
        ldsO[i] = ch * 8;                // linear LDS dest (wave-uniform base + lane*16B)
    }

    const int lane = t & 63;
    const int wv   = t >> 6;
    const int wm   = (wv >> 1) * 64;
    const int wn   = (wv & 1) * 64;
    const int rr   = lane & 15;
    const int g    = lane >> 4;

    f32x4 acc[4][4];
#pragma unroll
    for (int r = 0; r < 4; ++r)
#pragma unroll
        for (int cc = 0; cc < 4; ++cc)
            acc[r][cc] = (f32x4){0.f, 0.f, 0.f, 0.f};

    // precompute swizzled read rows (row*BK) and row&7 for the XOR
    int rowA[4], rowB[4];
#pragma unroll
    for (int r = 0; r < 4; ++r) {
        rowA[r] = wm + r * 16 + rr;
        rowB[r] = wn + r * 16 + rr;
    }

    const int NKT = DIMQ / BK;  // 16

    // prologue: stage k-tile 0 into buf 0, drain
#pragma unroll
    for (int i = 0; i < 4; ++i)
        __builtin_amdgcn_global_load_lds(aS[i], &sA[0][ldsO[i]], 16, 0, 0);
#pragma unroll
    for (int i = 0; i < 4; ++i)
        __builtin_amdgcn_global_load_lds(bS[i], &sB[0][ldsO[i]], 16, 0, 0);
    __syncthreads();

    int cur = 0;
    for (int kt = 0; kt < NKT; ++kt) {
        if (kt + 1 < NKT) {   // issue next tile into other buffer BEFORE compute
            int kof = (kt + 1) * BK;
#pragma unroll
            for (int i = 0; i < 4; ++i)
                __builtin_amdgcn_global_load_lds(aS[i] + kof, &sA[cur ^ 1][ldsO[i]], 16, 0, 0);
#pragma unroll
            for (int i = 0; i < 4; ++i)
                __builtin_amdgcn_global_load_lds(bS[i] + kof, &sB[cur ^ 1][ldsO[i]], 16, 0, 0);
        }

#pragma unroll
        for (int ks = 0; ks < 2; ++ks) {
            bf16x8 af[4], bfr[4];
#pragma unroll
            for (int r = 0; r < 4; ++r) {
                int oA = (ks * 32 + g * 8) ^ ((rowA[r] & 7) * 8);   // swizzled read offset
                int oB = (ks * 32 + g * 8) ^ ((rowB[r] & 7) * 8);
                af[r]  = *reinterpret_cast<const bf16x8*>(&sA[cur][rowA[r] * BK + oA]);
                bfr[r] = *reinterpret_cast<const bf16x8*>(&sB[cur][rowB[r] * BK + oB]);
            }
#pragma unroll
            for (int r = 0; r < 4; ++r)
#pragma unroll
                for (int cc = 0; cc < 4; ++cc)
                    acc[r][cc] = __builtin_amdgcn_mfma_f32_16x16x32_bf16(af[r], bfr[cc], acc[r][cc], 0, 0, 0);
        }

        __syncthreads();   // drains vmcnt (next-tile stage) + lgkm; loads had the MFMA phase to land
        cur ^= 1;
    }

    // epilogue: gate-scale + scatter-add (each out element hit by exactly 2 charts)
#pragma unroll
    for (int r = 0; r < 4; ++r) {
#pragma unroll
        for (int cc = 0; cc < 4; ++cc) {
#pragma unroll
            for (int j = 0; j < 4; ++j) {
                int rowInTile = wm + r * 16 + g * 4 + j;   // C/D: row=(lane>>4)*4+reg, col=lane&15 (m89)
                int gi = m0 + rowInTile;
                if (gi < count) {
                    int   orow = sRow[rowInTile];
                    float wgx  = sW[rowInTile];
                    int   col  = n0 + wn + cc * 16 + rr;
                    atomicAdd(&out[(size_t)orow * DIMU + col], acc[r][cc][j] * wgx);
                }
            }
        }
    }
}

// ================= fallback f32-staging GEMM (proven round-2 path) =================
#define BKF 32
#define LDSTRF 40

__global__ __launch_bounds__(256, 2) void moe_gemm_f32(
    const float* __restrict__ q, const float* __restrict__ Wst,
    const int* __restrict__ cnt, const int* __restrict__ rowlist,
    const float* __restrict__ wgt, float* __restrict__ out)
{
    const int c  = blockIdx.z;
    const int n0 = blockIdx.x * BN;
    const int m0 = blockIdx.y * BM;
    const int count = cnt[c];
    if (m0 >= count) return;

    __shared__ short sA[BM * LDSTRF];
    __shared__ short sB[BN * LDSTRF];
    __shared__ int   sRow[BM];
    __shared__ float sW[BM];

    const int t = threadIdx.x;
    if (t < BM) {
        int gi = m0 + t;
        int r = 0; float w = 0.f;
        if (gi < count) {
            r = rowlist[(size_t)c * NROWS + gi];
            w = wgt[(size_t)c * NROWS + gi];
        }
        sRow[t] = r; sW[t] = w;
    }
    __syncthreads();

    const float* aBase[4];
    const float* bBase[4];
    int ldsOff[4];
#pragma unroll
    for (int i = 0; i < 4; ++i) {
        int f  = t + i * 256;
        int r  = f >> 3;
        int c4 = f & 7;
        aBase[i]  = q   + (size_t)sRow[r] * DIMQ + c4 * 4;
        bBase[i]  = Wst + (size_t)c * ((size_t)DIMU * DIMQ) + (size_t)(n0 + r) * DIMQ + c4 * 4;
        ldsOff[i] = r * LDSTRF + c4 * 4;
    }

    const int lane = t & 63;
    const int wv   = t >> 6;
    const int wm   = (wv >> 1) * 64;
    const int wn   = (wv & 1) * 64;
    const int rr   = lane & 15;
    const int g    = lane >> 4;

    f32x4 acc[4][4];
#pragma unroll
    for (int r = 0; r < 4; ++r)
#pragma unroll
        for (int cc = 0; cc < 4; ++cc)
            acc[r][cc] = (f32x4){0.f, 0.f, 0.f, 0.f};

    f32x4 pa[4], pb[4];
#pragma unroll
    for (int i = 0; i < 4; ++i) {
        pa[i] = *reinterpret_cast<const f32x4*>(aBase[i]);
        pb[i] = *reinterpret_cast<const f32x4*>(bBase[i]);
    }

    const int NKT = DIMQ / BKF;
    for (int kt = 0; kt < NKT; ++kt) {
        __syncthreads();
#pragma unroll
        for (int i = 0; i < 4; ++i) {
            s16x4 va, vb;
#pragma unroll
            for (int j = 0; j < 4; ++j) { va[j] = f2bf(pa[i][j]); vb[j] = f2bf(pb[i][j]); }
            *reinterpret_cast<s16x4*>(&sA[ldsOff[i]]) = va;
            *reinterpret_cast<s16x4*>(&sB[ldsOff[i]]) = vb;
        }
        __syncthreads();

        if (kt + 1 < NKT) {
            int k = (kt + 1) * BKF;
#pragma unroll
            for (int i = 0; i < 4; ++i) {
                pa[i] = *reinterpret_cast<const f32x4*>(aBase[i] + k);
                pb[i] = *reinterpret_cast<const f32x4*>(bBase[i] + k);
            }
        }

        bf16x8 af[4], bfr[4];
#pragma unroll
        for (int r = 0; r < 4; ++r) {
            af[r]  = *reinterpret_cast<const bf16x8*>(&sA[(wm + r * 16 + rr) * LDSTRF + g * 8]);
            bfr[r] = *reinterpret_cast<const bf16x8*>(&sB[(wn + r * 16 + rr) * LDSTRF + g * 8]);
        }
#pragma unroll
        for (int r = 0; r < 4; ++r)
#pragma unroll
            for (int cc = 0; cc < 4; ++cc)
                acc[r][cc] = __builtin_amdgcn_mfma_f32_16x16x32_bf16(af[r], bfr[cc], acc[r][cc], 0, 0, 0);
    }

#pragma unroll
    for (int r = 0; r < 4; ++r) {
#pragma unroll
        for (int cc = 0; cc < 4; ++cc) {
#pragma unroll
            for (int j = 0; j < 4; ++j) {
                int rowInTile = wm + r * 16 + g * 4 + j;
                int gi = m0 + rowInTile;
                if (gi < count) {
                    int   orow = sRow[rowInTile];
                    float w    = sW[rowInTile];
                    int   col  = n0 + wn + cc * 16 + rr;
                    atomicAdd(&out[(size_t)orow * DIMU + col], acc[r][cc][j] * w);
                }
            }
        }
    }
}

extern "C" void kernel_launch(void* const* d_in, const int* in_sizes, int n_in,
                              void* d_out, int out_size, void* d_ws, size_t ws_size,
                              hipStream_t stream) {
    const float* q  = (const float*)d_in[0];
    const float* w  = (const float*)d_in[1];
    const float* Ws = (const float*)d_in[2];
    float* out = (float*)d_out;

    const size_t qbf_bytes  = (size_t)NROWS * DIMQ * 2;              // 16.78 MB
    const size_t wbf_bytes  = (size_t)NCH * DIMU * (size_t)DIMQ * 2; // 33.55 MB
    const size_t meta_bytes = 256 + (size_t)NCH * NROWS * (sizeof(int) + sizeof(float));
    char* ws = (char*)d_ws;

    if (ws_size >= qbf_bytes + wbf_bytes + meta_bytes) {
        short* qb      = (short*)ws;
        short* Wb      = (short*)(ws + qbf_bytes);
        int*   cnt     = (int*)(ws + qbf_bytes + wbf_bytes);
        int*   rowlist = (int*)(ws + qbf_bytes + wbf_bytes + 256);
        float* wgt     = (float*)(ws + qbf_bytes + wbf_bytes + 256 + (size_t)NCH * NROWS * sizeof(int));

        hipMemsetAsync(cnt, 0, 256, stream);
        hipMemsetAsync(d_out, 0, (size_t)out_size * sizeof(float), stream);

        cvt2_kernel<<<2048, 256, 0, stream>>>(q, Ws, qb, Wb);
        gate_kernel<<<NROWS / 256, 256, 0, stream>>>(w, cnt, rowlist, wgt);

        dim3 grid(DIMU / BN, NROWS / BM, NCH);   // R3 measured-best grid shape
        moe_gemm_bf<<<grid, 256, 0, stream>>>(qb, Wb, cnt, rowlist, wgt, out);
    } else {
        int*   cnt     = (int*)ws;
        int*   rowlist = (int*)(ws + 256);
        float* wgt     = (float*)(ws + 256 + (size_t)NCH * NROWS * sizeof(int));

        hipMemsetAsync(cnt, 0, 256, stream);
        hipMemsetAsync(d_out, 0, (size_t)out_size * sizeof(float), stream);

        gate_kernel<<<NROWS / 256, 256, 0, stream>>>(w, cnt, rowlist, wgt);

        dim3 grid(DIMU / BN, NROWS / BM, NCH);
        moe_gemm_f32<<<grid, 256, 0, stream>>>(q, Ws, cnt, rowlist, wgt, out);
    }
}

// Round 9
// 228.466 us; speedup vs baseline: 1.0809x; 1.0766x over previous
//
#include <hip/hip_runtime.h>
#include <hip/hip_bf16.h>
#include <stdint.h>

#define NROWS 8192
#define DIMQ 1024
#define DIMU 1024
#define NCH 16

#define BM 128
#define BN 128
#define BK 64
#define LDSTR 72   // padded LDS row: 144B stride, b128 ops spread across bank groups (R3-proven)

typedef __attribute__((ext_vector_type(4))) float f32x4;
typedef __attribute__((ext_vector_type(4))) short s16x4;
typedef __attribute__((ext_vector_type(8))) short bf16x8;

__device__ __forceinline__ short f2bf(float f) {
    union { __hip_bfloat16 h; short s; } u;
    u.h = __float2bfloat16(f);
    return u.s;
}

// ---------------- fused f32 -> bf16 convert for q and W_stack (R3 proven) ----------------
__global__ void cvt2_kernel(const float* __restrict__ q, const float* __restrict__ Ws,
                            short* __restrict__ qb, short* __restrict__ Wb) {
    const int nq = NROWS * DIMQ / 8;
    const int nw = NCH * DIMU * DIMQ / 8;
    int i0 = blockIdx.x * blockDim.x + threadIdx.x;
    int stride = gridDim.x * blockDim.x;
    for (int i = i0; i < nq; i += stride) {
        const f32x4* p = reinterpret_cast<const f32x4*>(q + (size_t)i * 8);
        f32x4 a = p[0], b = p[1];
        bf16x8 o;
        o[0] = f2bf(a[0]); o[1] = f2bf(a[1]); o[2] = f2bf(a[2]); o[3] = f2bf(a[3]);
        o[4] = f2bf(b[0]); o[5] = f2bf(b[1]); o[6] = f2bf(b[2]); o[7] = f2bf(b[3]);
        *reinterpret_cast<bf16x8*>(qb + (size_t)i * 8) = o;
    }
    for (int i = i0; i < nw; i += stride) {
        const f32x4* p = reinterpret_cast<const f32x4*>(Ws + (size_t)i * 8);
        f32x4 a = p[0], b = p[1];
        bf16x8 o;
        o[0] = f2bf(a[0]); o[1] = f2bf(a[1]); o[2] = f2bf(a[2]); o[3] = f2bf(a[3]);
        o[4] = f2bf(b[0]); o[5] = f2bf(b[1]); o[6] = f2bf(b[2]); o[7] = f2bf(b[3]);
        *reinterpret_cast<bf16x8*>(Wb + (size_t)i * 8) = o;
    }
}

// ---------------- gate: top-2 + normalize, LDS histogram ----------------
__global__ void gate_kernel(const float* __restrict__ weights,
                            int* __restrict__ cnt,
                            int* __restrict__ rowlist,
                            float* __restrict__ wgt) {
    __shared__ int lcnt[NCH];
    __shared__ int lbase[NCH];
    const int t = threadIdx.x;
    const int b = blockIdx.x * blockDim.x + t;
    if (t < NCH) lcnt[t] = 0;
    __syncthreads();

    float w[NCH];
    const f32x4* wp = reinterpret_cast<const f32x4*>(weights + (size_t)b * NCH);
#pragma unroll
    for (int i = 0; i < 4; ++i) {
        f32x4 v = wp[i];
        w[i * 4 + 0] = v[0]; w[i * 4 + 1] = v[1];
        w[i * 4 + 2] = v[2]; w[i * 4 + 3] = v[3];
    }
    int i0 = 0; float v0 = w[0];
#pragma unroll
    for (int i = 1; i < NCH; ++i) if (w[i] > v0) { v0 = w[i]; i0 = i; }
    int i1 = (i0 == 0) ? 1 : 0; float v1 = w[i1];
#pragma unroll
    for (int i = 0; i < NCH; ++i) if (i != i0 && w[i] > v1) { v1 = w[i]; i1 = i; }
    float s = v0 + v1;
    s = (s < 1e-8f) ? 1e-8f : s;
    float n0 = v0 / s, n1 = v1 / s;

    int p0 = atomicAdd(&lcnt[i0], 1);
    int p1 = atomicAdd(&lcnt[i1], 1);
    __syncthreads();
    if (t < NCH) lbase[t] = atomicAdd(&cnt[t], lcnt[t]);
    __syncthreads();

    int o0 = lbase[i0] + p0;
    int o1 = lbase[i1] + p1;
    rowlist[(size_t)i0 * NROWS + o0] = b;  wgt[(size_t)i0 * NROWS + o0] = n0;
    rowlist[(size_t)i1 * NROWS + o1] = b;  wgt[(size_t)i1 * NROWS + o1] = n1;
}

// ================= bf16 grouped gather-GEMM — R3 structure, 8-wave + 2-deep prefetch =================
// 512 threads / 8 waves (wave-tile 64x32, acc[4][2]): halves per-wave VGPR -> 16 waves/CU.
// 2-deep register prefetch (named A0/A1,B0/B1, statically unrolled x2 per rule #20):
// each global load issued TWO K-steps before its LDS write (~700cy in flight).
__global__ __launch_bounds__(512, 4) void moe_gemm_bf(
    const short* __restrict__ qb, const short* __restrict__ Wb,
    const int* __restrict__ cnt, const int* __restrict__ rowlist,
    const float* __restrict__ wgt, float* __restrict__ out)
{
    const int c  = blockIdx.z;
    const int n0 = blockIdx.x * BN;
    const int m0 = blockIdx.y * BM;
    const int count = cnt[c];
    if (m0 >= count) return;

    __shared__ short sA[BM * LDSTR];   // 18 KB
    __shared__ short sB[BN * LDSTR];   // 18 KB
    __shared__ int   sRow[BM];
    __shared__ float sW[BM];

    const int t = threadIdx.x;
    if (t < BM) {
        int gi = m0 + t;
        int r = 0; float wv_ = 0.f;
        if (gi < count) {
            r   = rowlist[(size_t)c * NROWS + gi];
            wv_ = wgt[(size_t)c * NROWS + gi];
        }
        sRow[t] = r; sW[t] = wv_;
    }
    __syncthreads();

    // staging: tile = 128 rows x 64 bf16 = 1024 x 16B chunks; 2 chunks/thread/matrix
    const short* aS[2];
    const short* bS[2];
    int ldsO[2];
#pragma unroll
    for (int i = 0; i < 2; ++i) {
        int ch = i * 512 + t;
        int r  = ch >> 3;
        int c8 = ch & 7;
        aS[i]   = qb + (size_t)sRow[r] * DIMQ + c8 * 8;
        bS[i]   = Wb + (size_t)c * ((size_t)DIMU * DIMQ) + (size_t)(n0 + r) * DIMQ + c8 * 8;
        ldsO[i] = r * LDSTR + c8 * 8;
    }

    const int lane = t & 63;
    const int wv   = t >> 6;            // 0..7
    const int wm   = (wv >> 2) * 64;    // 2 wave-rows
    const int wn   = (wv & 3) * 32;     // 4 wave-cols
    const int rr   = lane & 15;
    const int g    = lane >> 4;

    f32x4 acc[4][2];
#pragma unroll
    for (int r = 0; r < 4; ++r)
#pragma unroll
        for (int n = 0; n < 2; ++n)
            acc[r][n] = (f32x4){0.f, 0.f, 0.f, 0.f};

    // 2-deep prefetch registers (static names, no runtime indexing)
    bf16x8 a0[2], b0[2], a1[2], b1[2];
#pragma unroll
    for (int i = 0; i < 2; ++i) {
        a0[i] = *reinterpret_cast<const bf16x8*>(aS[i]);
        b0[i] = *reinterpret_cast<const bf16x8*>(bS[i]);
        a1[i] = *reinterpret_cast<const bf16x8*>(aS[i] + BK);
        b1[i] = *reinterpret_cast<const bf16x8*>(bS[i] + BK);
    }

#define COMPUTE_STEP()                                                                              \
    {                                                                                               \
        _Pragma("unroll")                                                                           \
        for (int ks = 0; ks < 2; ++ks) {                                                            \
            bf16x8 af[4], bfr[2];                                                                   \
            _Pragma("unroll")                                                                       \
            for (int r = 0; r < 4; ++r)                                                             \
                af[r]  = *reinterpret_cast<const bf16x8*>(&sA[(wm + r * 16 + rr) * LDSTR + ks * 32 + g * 8]); \
            _Pragma("unroll")                                                                       \
            for (int n = 0; n < 2; ++n)                                                             \
                bfr[n] = *reinterpret_cast<const bf16x8*>(&sB[(wn + n * 16 + rr) * LDSTR + ks * 32 + g * 8]); \
            _Pragma("unroll")                                                                       \
            for (int r = 0; r < 4; ++r)                                                             \
                _Pragma("unroll")                                                                   \
                for (int n = 0; n < 2; ++n)                                                         \
                    acc[r][n] = __builtin_amdgcn_mfma_f32_16x16x32_bf16(af[r], bfr[n], acc[r][n], 0, 0, 0); \
        }                                                                                           \
    }

    const int NKT = DIMQ / BK;  // 16, even
    for (int kt2 = 0; kt2 < NKT; kt2 += 2) {
        // ---- even step: consume A0/B0 ----
        __syncthreads();
#pragma unroll
        for (int i = 0; i < 2; ++i) {
            *reinterpret_cast<bf16x8*>(&sA[ldsO[i]]) = a0[i];
            *reinterpret_cast<bf16x8*>(&sB[ldsO[i]]) = b0[i];
        }
        __syncthreads();
        if (kt2 + 2 < NKT) {          // refill slot 0 for K-step kt2+2 (2 phases ahead)
            int k = (kt2 + 2) * BK;
#pragma unroll
            for (int i = 0; i < 2; ++i) {
                a0[i] = *reinterpret_cast<const bf16x8*>(aS[i] + k);
                b0[i] = *reinterpret_cast<const bf16x8*>(bS[i] + k);
            }
        }
        COMPUTE_STEP();

        // ---- odd step: consume A1/B1 ----
        __syncthreads();
#pragma unroll
        for (int i = 0; i < 2; ++i) {
            *reinterpret_cast<bf16x8*>(&sA[ldsO[i]]) = a1[i];
            *reinterpret_cast<bf16x8*>(&sB[ldsO[i]]) = b1[i];
        }
        __syncthreads();
        if (kt2 + 3 < NKT) {          // refill slot 1 for K-step kt2+3
            int k = (kt2 + 3) * BK;
#pragma unroll
            for (int i = 0; i < 2; ++i) {
                a1[i] = *reinterpret_cast<const bf16x8*>(aS[i] + k);
                b1[i] = *reinterpret_cast<const bf16x8*>(bS[i] + k);
            }
        }
        COMPUTE_STEP();
    }
#undef COMPUTE_STEP

    // epilogue: gate-scale + scatter-add (each out element hit by exactly 2 charts)
#pragma unroll
    for (int r = 0; r < 4; ++r) {
#pragma unroll
        for (int n = 0; n < 2; ++n) {
#pragma unroll
            for (int j = 0; j < 4; ++j) {
                int rowInTile = wm + r * 16 + g * 4 + j;   // C/D: row=(lane>>4)*4+reg, col=lane&15 (m89)
                int gi = m0 + rowInTile;
                if (gi < count) {
                    int   orow = sRow[rowInTile];
                    float wgx  = sW[rowInTile];
                    int   col  = n0 + wn + n * 16 + rr;
                    atomicAdd(&out[(size_t)orow * DIMU + col], acc[r][n][j] * wgx);
                }
            }
        }
    }
}

// ================= fallback f32-staging GEMM (proven round-2 path) =================
#define BKF 32
#define LDSTRF 40

__global__ __launch_bounds__(256, 2) void moe_gemm_f32(
    const float* __restrict__ q, const float* __restrict__ Wst,
    const int* __restrict__ cnt, const int* __restrict__ rowlist,
    const float* __restrict__ wgt, float* __restrict__ out)
{
    const int c  = blockIdx.z;
    const int n0 = blockIdx.x * BN;
    const int m0 = blockIdx.y * BM;
    const int count = cnt[c];
    if (m0 >= count) return;

    __shared__ short sA[BM * LDSTRF];
    __shared__ short sB[BN * LDSTRF];
    __shared__ int   sRow[BM];
    __shared__ float sW[BM];

    const int t = threadIdx.x;
    if (t < BM) {
        int gi = m0 + t;
        int r = 0; float w = 0.f;
        if (gi < count) {
            r = rowlist[(size_t)c * NROWS + gi];
            w = wgt[(size_t)c * NROWS + gi];
        }
        sRow[t] = r; sW[t] = w;
    }
    __syncthreads();

    const float* aBase[4];
    const float* bBase[4];
    int ldsOff[4];
#pragma unroll
    for (int i = 0; i < 4; ++i) {
        int f  = t + i * 256;
        int r  = f >> 3;
        int c4 = f & 7;
        aBase[i]  = q   + (size_t)sRow[r] * DIMQ + c4 * 4;
        bBase[i]  = Wst + (size_t)c * ((size_t)DIMU * DIMQ) + (size_t)(n0 + r) * DIMQ + c4 * 4;
        ldsOff[i] = r * LDSTRF + c4 * 4;
    }

    const int lane = t & 63;
    const int wv   = t >> 6;
    const int wm   = (wv >> 1) * 64;
    const int wn   = (wv & 1) * 64;
    const int rr   = lane & 15;
    const int g    = lane >> 4;

    f32x4 acc[4][4];
#pragma unroll
    for (int r = 0; r < 4; ++r)
#pragma unroll
        for (int cc = 0; cc < 4; ++cc)
            acc[r][cc] = (f32x4){0.f, 0.f, 0.f, 0.f};

    f32x4 pa[4], pb[4];
#pragma unroll
    for (int i = 0; i < 4; ++i) {
        pa[i] = *reinterpret_cast<const f32x4*>(aBase[i]);
        pb[i] = *reinterpret_cast<const f32x4*>(bBase[i]);
    }

    const int NKT = DIMQ / BKF;
    for (int kt = 0; kt < NKT; ++kt) {
        __syncthreads();
#pragma unroll
        for (int i = 0; i < 4; ++i) {
            s16x4 va, vb;
#pragma unroll
            for (int j = 0; j < 4; ++j) { va[j] = f2bf(pa[i][j]); vb[j] = f2bf(pb[i][j]); }
            *reinterpret_cast<s16x4*>(&sA[ldsOff[i]]) = va;
            *reinterpret_cast<s16x4*>(&sB[ldsOff[i]]) = vb;
        }
        __syncthreads();

        if (kt + 1 < NKT) {
            int k = (kt + 1) * BKF;
#pragma unroll
            for (int i = 0; i < 4; ++i) {
                pa[i] = *reinterpret_cast<const f32x4*>(aBase[i] + k);
                pb[i] = *reinterpret_cast<const f32x4*>(bBase[i] + k);
            }
        }

        bf16x8 af[4], bfr[4];
#pragma unroll
        for (int r = 0; r < 4; ++r) {
            af[r]  = *reinterpret_cast<const bf16x8*>(&sA[(wm + r * 16 + rr) * LDSTRF + g * 8]);
            bfr[r] = *reinterpret_cast<const bf16x8*>(&sB[(wn + r * 16 + rr) * LDSTRF + g * 8]);
        }
#pragma unroll
        for (int r = 0; r < 4; ++r)
#pragma unroll
            for (int cc = 0; cc < 4; ++cc)
                acc[r][cc] = __builtin_amdgcn_mfma_f32_16x16x32_bf16(af[r], bfr[cc], acc[r][cc], 0, 0, 0);
    }

#pragma unroll
    for (int r = 0; r < 4; ++r) {
#pragma unroll
        for (int cc = 0; cc < 4; ++cc) {
#pragma unroll
            for (int j = 0; j < 4; ++j) {
                int rowInTile = wm + r * 16 + g * 4 + j;
                int gi = m0 + rowInTile;
                if (gi < count) {
                    int   orow = sRow[rowInTile];
                    float w    = sW[rowInTile];
                    int   col  = n0 + wn + cc * 16 + rr;
                    atomicAdd(&out[(size_t)orow * DIMU + col], acc[r][cc][j] * w);
                }
            }
        }
    }
}

extern "C" void kernel_launch(void* const* d_in, const int* in_sizes, int n_in,
                              void* d_out, int out_size, void* d_ws, size_t ws_size,
                              hipStream_t stream) {
    const float* q  = (const float*)d_in[0];
    const float* w  = (const float*)d_in[1];
    const float* Ws = (const float*)d_in[2];
    float* out = (float*)d_out;

    const size_t qbf_bytes  = (size_t)NROWS * DIMQ * 2;              // 16.78 MB
    const size_t wbf_bytes  = (size_t)NCH * DIMU * (size_t)DIMQ * 2; // 33.55 MB
    const size_t meta_bytes = 256 + (size_t)NCH * NROWS * (sizeof(int) + sizeof(float));
    char* ws = (char*)d_ws;

    if (ws_size >= qbf_bytes + wbf_bytes + meta_bytes) {
        short* qb      = (short*)ws;
        short* Wb      = (short*)(ws + qbf_bytes);
        int*   cnt     = (int*)(ws + qbf_bytes + wbf_bytes);
        int*   rowlist = (int*)(ws + qbf_bytes + wbf_bytes + 256);
        float* wgt     = (float*)(ws + qbf_bytes + wbf_bytes + 256 + (size_t)NCH * NROWS * sizeof(int));

        hipMemsetAsync(cnt, 0, 256, stream);
        hipMemsetAsync(d_out, 0, (size_t)out_size * sizeof(float), stream);

        cvt2_kernel<<<2048, 256, 0, stream>>>(q, Ws, qb, Wb);
        gate_kernel<<<NROWS / 256, 256, 0, stream>>>(w, cnt, rowlist, wgt);

        dim3 grid(DIMU / BN, NROWS / BM, NCH);   // R3 measured-best grid shape
        moe_gemm_bf<<<grid, 512, 0, stream>>>(qb, Wb, cnt, rowlist, wgt, out);
    } else {
        int*   cnt     = (int*)ws;
        int*   rowlist = (int*)(ws + 256);
        float* wgt     = (float*)(ws + 256 + (size_t)NCH * NROWS * sizeof(int));

        hipMemsetAsync(cnt, 0, 256, stream);
        hipMemsetAsync(d_out, 0, (size_t)out_size * sizeof(float), stream);

        gate_kernel<<<NROWS / 256, 256, 0, stream>>>(w, cnt, rowlist, wgt);

        dim3 grid(DIMU / BN, NROWS / BM, NCH);
        moe_gemm_f32<<<grid, 256, 0, stream>>>(q, Ws, cnt, rowlist, wgt, out);
    }
}